// Round 9
// baseline (433.128 us; speedup 1.0000x reference)
//
#include <hip/hip_runtime.h>
#include <hip/hip_bf16.h>

#define BATCH 32768
#define TT 11
#define EE 128
#define HH 20

typedef unsigned short ushort_t;
typedef __attribute__((ext_vector_type(8))) short short8;
typedef __attribute__((ext_vector_type(4))) float f32x4;

// ws layout (bytes):
//   [0 .. 8192)          : double slots[1024]
//   [8192 ..)            : float zc  [T][H][B]   (28835840)
//   [+..]                : float hist[T][H][B]   (28835840)
//   [+..]                : float hs  [H][B]      (2621440)
//   [+..]                : weight fragment region (2-split A-operands)
#define ZC_OFF   8192
#define HIST_OFF (8192 + 28835840)
#define HS_OFF   (8192 + 2*28835840)
#define W1A_OFF  (HS_OFF + 2621440)            // [4kt][4nt][2sp][64][4] u32 = 32768 B
#define W2A_OFF  (W1A_OFF + 32768)             // [2kt][7nt][2sp][64][4] u32 = 28672 B
#define CA_OFF   (W2A_OFF + 28672)             // [4kt][2nt][2sp][64][4] u32 = 16384 B
#define B1F_OFF  (CA_OFF + 16384)              // [4nt][64][4] f32 = 16384 B
#define B2F_OFF  (B1F_OFF + 16384)             // [7nt][64][4] f32 = 28672 B

__device__ __forceinline__ float waveRed(float v) {
    #pragma unroll
    for (int m = 32; m > 0; m >>= 1) v += __shfl_xor(v, m, 64);
    return v;
}

// 2-way bf16 split: v = h1 + h2 + O(2^-18 v)
__device__ __forceinline__ void split2(float v, ushort_t& a, ushort_t& b) {
    __hip_bfloat16 h1 = __float2bfloat16(v);
    float r1 = v - __bfloat162float(h1);     // exact (Sterbenz)
    __hip_bfloat16 h2 = __float2bfloat16(r1);
    a = *(ushort_t*)&h1; b = *(ushort_t*)&h2;
}

__device__ __forceinline__ f32x4 mfma16(short8 a, short8 b, f32x4 c) {
    return __builtin_amdgcn_mfma_f32_16x16x32_bf16(a, b, c, 0, 0, 0);
}

union FragU { uint4 v; unsigned int u[4]; short8 s; };

// ---------------- setup: pre-fragment weights (A-operand, 2 splits) + bias frags + zero slots ----------------
__global__ __launch_bounds__(256) void setup_kernel(
    const float* __restrict__ w1, const float* __restrict__ b1,
    const float* __restrict__ w2, const float* __restrict__ b2,
    const float* __restrict__ c,
    unsigned int* __restrict__ W1A, unsigned int* __restrict__ W2A, unsigned int* __restrict__ CA,
    float* __restrict__ b1f, float* __restrict__ b2f, double* __restrict__ slots)
{
    const int gid = blockIdx.x * 256 + threadIdx.x;
    const int nth = gridDim.x * 256;
    for (int i = gid; i < 1024; i += nth) slots[i] = 0.0;

    for (int i = gid; i < 4096; i += nth) {
        const int r = i & 3, lane = (i >> 2) & 63, nt = (i >> 8) & 3, kt = i >> 10;
        const int m = nt * 16 + (lane & 15);
        const int g = lane >> 4;
        int j0 = 2 * r, j1 = 2 * r + 1;
        int k0 = kt * 32 + ((j0 >= 4) ? 16 : 0) + 4 * g + (j0 & 3);
        int k1 = kt * 32 + ((j1 >= 4) ? 16 : 0) + 4 * g + (j1 & 3);
        float v0 = (m < 50) ? w1[k0 * 50 + m] : 0.f;
        float v1 = (m < 50) ? w1[k1 * 50 + m] : 0.f;
        ushort_t a0, a1, c0, c1;
        split2(v0, a0, a1); split2(v1, c0, c1);
        W1A[(((kt * 4 + nt) * 2 + 0) * 64 + lane) * 4 + r] = a0 | ((unsigned)c0 << 16);
        W1A[(((kt * 4 + nt) * 2 + 1) * 64 + lane) * 4 + r] = a1 | ((unsigned)c1 << 16);
    }
    for (int i = gid; i < 3584; i += nth) {
        const int r = i & 3, lane = (i >> 2) & 63, rest = i >> 8;
        const int nt = rest % 7, kt = rest / 7;
        const int m = nt * 16 + (lane & 15);
        const int g = lane >> 4;
        int j0 = 2 * r, j1 = 2 * r + 1;
        int k0 = kt * 32 + ((j0 >= 4) ? 16 : 0) + 4 * g + (j0 & 3);
        int k1 = kt * 32 + ((j1 >= 4) ? 16 : 0) + 4 * g + (j1 & 3);
        float v0 = (m < 100 && k0 < 50) ? w2[k0 * 100 + m] : 0.f;
        float v1 = (m < 100 && k1 < 50) ? w2[k1 * 100 + m] : 0.f;
        ushort_t a0, a1, c0, c1;
        split2(v0, a0, a1); split2(v1, c0, c1);
        W2A[(((kt * 7 + nt) * 2 + 0) * 64 + lane) * 4 + r] = a0 | ((unsigned)c0 << 16);
        W2A[(((kt * 7 + nt) * 2 + 1) * 64 + lane) * 4 + r] = a1 | ((unsigned)c1 << 16);
    }
    for (int i = gid; i < 2048; i += nth) {
        const int r = i & 3, lane = (i >> 2) & 63, rest = i >> 8;
        const int nt = rest & 1, kt = rest >> 1;
        const int m = nt * 16 + (lane & 15);
        const int g = lane >> 4;
        int j0 = 2 * r, j1 = 2 * r + 1;
        int k0 = kt * 32 + ((j0 >= 4) ? 16 : 0) + 4 * g + (j0 & 3);
        int k1 = kt * 32 + ((j1 >= 4) ? 16 : 0) + 4 * g + (j1 & 3);
        float v0 = (m < 20 && k0 < 100) ? c[k0 * 20 + m] : 0.f;
        float v1 = (m < 20 && k1 < 100) ? c[k1 * 20 + m] : 0.f;
        ushort_t a0, a1, c0, c1;
        split2(v0, a0, a1); split2(v1, c0, c1);
        CA[(((kt * 2 + nt) * 2 + 0) * 64 + lane) * 4 + r] = a0 | ((unsigned)c0 << 16);
        CA[(((kt * 2 + nt) * 2 + 1) * 64 + lane) * 4 + r] = a1 | ((unsigned)c1 << 16);
    }
    for (int i = gid; i < 1024; i += nth) {
        const int r = i & 3, lane = (i >> 2) & 63, nt = i >> 8;
        const int n = nt * 16 + 4 * (lane >> 4) + r;
        b1f[i] = (n < 50) ? b1[n] : 0.f;
    }
    for (int i = gid; i < 1792; i += nth) {
        const int r = i & 3, lane = (i >> 2) & 63, nt = i >> 8;
        const int n = nt * 16 + 4 * (lane >> 4) + r;
        b2f[i] = (n < 100) ? b2[n] : 0.f;
    }
}

// build B-frag pair (2 splits) from the two float4s of one kt chunk
__device__ __forceinline__ void buildB(const float4 lo, const float4 hi, FragU& B0, FragU& B1) {
    ushort_t a[8], b[8];
    split2(lo.x, a[0], b[0]); split2(lo.y, a[1], b[1]);
    split2(lo.z, a[2], b[2]); split2(lo.w, a[3], b[3]);
    split2(hi.x, a[4], b[4]); split2(hi.y, a[5], b[5]);
    split2(hi.z, a[6], b[6]); split2(hi.w, a[7], b[7]);
    #pragma unroll
    for (int r = 0; r < 4; ++r) {
        B0.u[r] = a[2 * r] | ((unsigned)a[2 * r + 1] << 16);
        B1.u[r] = b[2 * r] | ((unsigned)b[2 * r + 1] << 16);
    }
}

// bias+relu+split of one D quadrant into B-frag halves (identical math to R8)
__device__ __forceinline__ void actSplit(const f32x4 D, const float4 bv, int half, FragU* B) {
    #pragma unroll
    for (int rp = 0; rp < 2; ++rp) {
        float v0 = fmaxf(D[2 * rp]     + bv[2 * rp],     0.f);
        float v1 = fmaxf(D[2 * rp + 1] + bv[2 * rp + 1], 0.f);
        ushort_t s00, s01, s10, s11;
        split2(v0, s00, s01); split2(v1, s10, s11);
        B[0].u[half * 2 + rp] = s00 | ((unsigned)s10 << 16);
        B[1].u[half * 2 + rp] = s01 | ((unsigned)s11 << 16);
    }
}

// ---------------- MFMA input MLP v3: register-direct B-frags (no LDS), 2 m-tiles per wave ----------------
// Each wave: 32 sample-rows (two 16-row tiles sharing every A-fragment load -> half the L2 weight traffic).
__global__ __launch_bounds__(256) void mlp_mfma(
    const float* __restrict__ bx,
    const unsigned int* __restrict__ W1A, const unsigned int* __restrict__ W2A,
    const unsigned int* __restrict__ CA,
    const float* __restrict__ b1f, const float* __restrict__ b2f,
    float* __restrict__ zc)
{
    const int tid = threadIdx.x;
    const int lane = tid & 63, wv = tid >> 6;
    const int R = (blockIdx.x * 4 + wv) * 32;     // 2816 blocks * 4 waves * 32 rows
    const int t = R >> 15;                         // 32768 rows per t; chunks never straddle t
    const int bbase = R & (BATCH - 1);
    const int srow = lane & 15, g = lane >> 4;

    const float* xp0 = bx + ((size_t)(bbase + srow) * TT + t) * EE;
    const float* xp1 = bx + ((size_t)(bbase + 16 + srow) * TT + t) * EE;

    // preload X: per lane 8 float4 per tile; each 16-lane g-group covers full 64B lines
    float4 xl0[4], xh0[4], xl1[4], xh1[4];
    #pragma unroll
    for (int kt = 0; kt < 4; ++kt) {
        xl0[kt] = *(const float4*)(xp0 + kt * 32 + 4 * g);
        xh0[kt] = *(const float4*)(xp0 + kt * 32 + 16 + 4 * g);
        xl1[kt] = *(const float4*)(xp1 + kt * 32 + 4 * g);
        xh1[kt] = *(const float4*)(xp1 + kt * 32 + 16 + 4 * g);
    }

    const uint4* W1A4 = (const uint4*)W1A;
    const uint4* W2A4 = (const uint4*)W2A;
    const uint4* CA4  = (const uint4*)CA;
    const float4* b1f4 = (const float4*)b1f;
    const float4* b2f4 = (const float4*)b2f;

    // ---- Layer 1 ----
    f32x4 D1a[4], D1b[4];
    #pragma unroll
    for (int nt = 0; nt < 4; ++nt) { D1a[nt] = (f32x4){0,0,0,0}; D1b[nt] = (f32x4){0,0,0,0}; }
    #pragma unroll
    for (int kt = 0; kt < 4; ++kt) {
        FragU Ba[2], Bb[2];
        buildB(xl0[kt], xh0[kt], Ba[0], Ba[1]);
        buildB(xl1[kt], xh1[kt], Bb[0], Bb[1]);
        #pragma unroll
        for (int nt = 0; nt < 4; ++nt) {
            FragU A0, A1;
            A0.v = W1A4[((kt * 4 + nt) * 2 + 0) * 64 + lane];
            A1.v = W1A4[((kt * 4 + nt) * 2 + 1) * 64 + lane];
            D1a[nt] = mfma16(A1.s, Ba[0].s, D1a[nt]);
            D1a[nt] = mfma16(A0.s, Ba[1].s, D1a[nt]);
            D1a[nt] = mfma16(A0.s, Ba[0].s, D1a[nt]);
            D1b[nt] = mfma16(A1.s, Bb[0].s, D1b[nt]);
            D1b[nt] = mfma16(A0.s, Bb[1].s, D1b[nt]);
            D1b[nt] = mfma16(A0.s, Bb[0].s, D1b[nt]);
        }
    }

    // ---- Layer 2 ----
    f32x4 D2a[7], D2b[7];
    #pragma unroll
    for (int nt = 0; nt < 7; ++nt) { D2a[nt] = (f32x4){0,0,0,0}; D2b[nt] = (f32x4){0,0,0,0}; }
    #pragma unroll
    for (int kt2 = 0; kt2 < 2; ++kt2) {
        FragU Ba[2], Bb[2];
        #pragma unroll
        for (int half = 0; half < 2; ++half) {
            const int nt = 2 * kt2 + half;
            const float4 bv = b1f4[nt * 64 + lane];
            actSplit(D1a[nt], bv, half, Ba);
            actSplit(D1b[nt], bv, half, Bb);
        }
        #pragma unroll
        for (int nt2 = 0; nt2 < 7; ++nt2) {
            FragU A0, A1;
            A0.v = W2A4[((kt2 * 7 + nt2) * 2 + 0) * 64 + lane];
            A1.v = W2A4[((kt2 * 7 + nt2) * 2 + 1) * 64 + lane];
            D2a[nt2] = mfma16(A1.s, Ba[0].s, D2a[nt2]);
            D2a[nt2] = mfma16(A0.s, Ba[1].s, D2a[nt2]);
            D2a[nt2] = mfma16(A0.s, Ba[0].s, D2a[nt2]);
            D2b[nt2] = mfma16(A1.s, Bb[0].s, D2b[nt2]);
            D2b[nt2] = mfma16(A0.s, Bb[1].s, D2b[nt2]);
            D2b[nt2] = mfma16(A0.s, Bb[0].s, D2b[nt2]);
        }
    }

    // ---- Layer 3 ----
    f32x4 D3a[2], D3b[2];
    D3a[0] = (f32x4){0,0,0,0}; D3a[1] = (f32x4){0,0,0,0};
    D3b[0] = (f32x4){0,0,0,0}; D3b[1] = (f32x4){0,0,0,0};
    #pragma unroll
    for (int kt3 = 0; kt3 < 4; ++kt3) {
        FragU Ba[2], Bb[2];
        #pragma unroll
        for (int half = 0; half < 2; ++half) {
            const int nt = 2 * kt3 + half;
            if (nt < 7) {
                const float4 bv = b2f4[nt * 64 + lane];
                actSplit(D2a[nt], bv, half, Ba);
                actSplit(D2b[nt], bv, half, Bb);
            } else {
                Ba[0].u[2] = Ba[0].u[3] = 0u; Ba[1].u[2] = Ba[1].u[3] = 0u;
                Bb[0].u[2] = Bb[0].u[3] = 0u; Bb[1].u[2] = Bb[1].u[3] = 0u;
            }
        }
        #pragma unroll
        for (int nt3 = 0; nt3 < 2; ++nt3) {
            FragU A0, A1;
            A0.v = CA4[((kt3 * 2 + nt3) * 2 + 0) * 64 + lane];
            A1.v = CA4[((kt3 * 2 + nt3) * 2 + 1) * 64 + lane];
            D3a[nt3] = mfma16(A1.s, Ba[0].s, D3a[nt3]);
            D3a[nt3] = mfma16(A0.s, Ba[1].s, D3a[nt3]);
            D3a[nt3] = mfma16(A0.s, Ba[0].s, D3a[nt3]);
            D3b[nt3] = mfma16(A1.s, Bb[0].s, D3b[nt3]);
            D3b[nt3] = mfma16(A0.s, Bb[1].s, D3b[nt3]);
            D3b[nt3] = mfma16(A0.s, Bb[0].s, D3b[nt3]);
        }
    }

    // ---- store zc (row-role = h, col = sample) for both tiles ----
    const int bcol0 = bbase + srow, bcol1 = bbase + 16 + srow;
    #pragma unroll
    for (int r = 0; r < 4; ++r) {
        const int h = 4 * g + r;
        zc[((size_t)(t * HH + h) << 15) + bcol0] = D3a[0][r];
        zc[((size_t)(t * HH + h) << 15) + bcol1] = D3b[0][r];
    }
    if (g == 0) {
        #pragma unroll
        for (int r = 0; r < 4; ++r) {
            zc[((size_t)(t * HH + 16 + r) << 15) + bcol0] = D3a[1][r];
            zc[((size_t)(t * HH + 16 + r) << 15) + bcol1] = D3b[1][r];
        }
    }
}

// ---------------- step kernel (template t): 2 lanes/sample, full-history register preload ----------------
// Same math/order as proven R6 version; all hist loads issue up-front (independent addresses)
// so the t dependent-latency exposures collapse to ~one. No min-wave cap: occupancy is
// structurally 1 block/CU (4 waves), so VGPR up to 256 is free.
template<int TC>
__global__ __launch_bounds__(256) void step_kernel(
    const float* __restrict__ zc, const float* __restrict__ lp, const float* __restrict__ ep,
    const float* __restrict__ w, const float* __restrict__ g, const float* __restrict__ bb,
    float* __restrict__ hist, float* __restrict__ hs_buf, double* __restrict__ slots)
{
    __shared__ float red[4][40];
    const int tid = threadIdx.x;
    const int p = tid & 1;
    const int sb = tid >> 1;
    const int b = blockIdx.x * 128 + sb;
    const int lane = tid & 63, wv = tid >> 6;
    const int jb = 10 * p;
    const float l0 = lp[0], e0 = ep[0];

    // issue ALL independent loads first: history, zc, prev hs
    float tv[TC > 0 ? TC : 1][10];
    #pragma unroll
    for (int s = 0; s < TC; ++s) {
        #pragma unroll
        for (int jj = 0; jj < 10; ++jj)
            tv[s][jj] = hist[((s * HH + jb + jj) << 15) + b];
    }
    float zct[10];
    #pragma unroll
    for (int jj = 0; jj < 10; ++jj) zct[jj] = zc[((TC * HH + jb + jj) << 15) + b];
    float hprev[10];
    if (TC > 0) {
        #pragma unroll
        for (int jj = 0; jj < 10; ++jj) hprev[jj] = hs_buf[((jb + jj) << 15) + b];
    }

    // carry h = BN(hs_{TC-1})
    float h[10];
    if (TC == 0) {
        #pragma unroll
        for (int jj = 0; jj < 10; ++jj) h[jj] = 0.f;
    } else {
        #pragma unroll
        for (int jj = 0; jj < 10; ++jj) {
            const int j = jb + jj;
            const double s1 = slots[(TC - 1) * 64 + j];
            const double s2 = slots[(TC - 1) * 64 + HH + j];
            const double mu = s1 * (1.0 / 32768.0);
            const double var = s2 * (1.0 / 32768.0) - mu * mu;
            const float muf = (float)mu;
            const float rsig = 1.0f / sqrtf((float)var);
            h[jj] = fmaxf(fmaf(g[j] * rsig, hprev[jj] - muf, bb[j]), 0.f);
        }
    }

    // hn = relu(h @ w + zc)
    float hn[10];
    {
        float po[20];
        #pragma unroll
        for (int j = 0; j < 20; ++j) {
            float a = 0.f;
            #pragma unroll
            for (int ii = 0; ii < 10; ++ii) a = fmaf(h[ii], w[(jb + ii) * HH + j], a);
            po[j] = a;
        }
        #pragma unroll
        for (int jj = 0; jj < 10; ++jj) {
            const float mine = p ? po[10 + jj] : po[jj];
            const float send = p ? po[jj] : po[10 + jj];
            const float recv = __shfl_xor(send, 1, 64);
            hn[jj] = fmaxf(mine + recv + zct[jj], 0.f);
        }
    }
    #pragma unroll
    for (int jj = 0; jj < 10; ++jj) hist[((TC * HH + jb + jj) << 15) + b] = hn[jj];

    // pv = e * sum_{s<=t} l^(t-s) (hn . hn_s) hn_s  (s descending, same order as R6)
    float pv[10];
    {
        float dp = 0.f;
        #pragma unroll
        for (int jj = 0; jj < 10; ++jj) dp = fmaf(hn[jj], hn[jj], dp);
        const float d = dp + __shfl_xor(dp, 1, 64);
        const float cd = e0 * d;
        #pragma unroll
        for (int jj = 0; jj < 10; ++jj) pv[jj] = cd * hn[jj];
    }
    if (TC > 0) {
        float coef = e0 * l0;
        #pragma unroll
        for (int si = 0; si < TC; ++si) {
            const int s = TC - 1 - si;
            float dp = 0.f;
            #pragma unroll
            for (int jj = 0; jj < 10; ++jj) dp = fmaf(hn[jj], tv[s][jj], dp);
            const float d = dp + __shfl_xor(dp, 1, 64);
            const float cd = coef * d;
            #pragma unroll
            for (int jj = 0; jj < 10; ++jj) pv[jj] = fmaf(cd, tv[s][jj], pv[jj]);
            coef *= l0;
        }
    }

    // hs = hn @ w + zc + pv
    float hs[10];
    {
        float po[20];
        #pragma unroll
        for (int j = 0; j < 20; ++j) {
            float a = 0.f;
            #pragma unroll
            for (int ii = 0; ii < 10; ++ii) a = fmaf(hn[ii], w[(jb + ii) * HH + j], a);
            po[j] = a;
        }
        #pragma unroll
        for (int jj = 0; jj < 10; ++jj) {
            const float mine = p ? po[10 + jj] : po[jj];
            const float send = p ? po[jj] : po[10 + jj];
            const float recv = __shfl_xor(send, 1, 64);
            hs[jj] = mine + recv + zct[jj] + pv[jj];
            hs_buf[((jb + jj) << 15) + b] = hs[jj];
        }
    }

    float sm[10], sq[10];
    #pragma unroll
    for (int jj = 0; jj < 10; ++jj) { sm[jj] = hs[jj]; sq[jj] = hs[jj] * hs[jj]; }
    #pragma unroll
    for (int m = 2; m <= 32; m <<= 1) {
        #pragma unroll
        for (int jj = 0; jj < 10; ++jj) {
            sm[jj] += __shfl_xor(sm[jj], m, 64);
            sq[jj] += __shfl_xor(sq[jj], m, 64);
        }
    }
    if (lane < 2) {
        #pragma unroll
        for (int jj = 0; jj < 10; ++jj) {
            red[wv][jb + jj] = sm[jj];
            red[wv][20 + jb + jj] = sq[jj];
        }
    }
    __syncthreads();
    if (tid < 40) {
        atomicAdd(&slots[TC * 64 + tid],
                  (double)(red[0][tid] + red[1][tid] + red[2][tid] + red[3][tid]));
    }
}

// ---------------- head: 4 waves co-operate on 64 samples (proven) ----------------
__global__ __launch_bounds__(256, 2) void head_kernel(
    const float* __restrict__ hs_buf, const float* __restrict__ by,
    const float* __restrict__ g, const float* __restrict__ bb,
    const float* __restrict__ w3, const float* __restrict__ b3,
    const float* __restrict__ w4, const float* __restrict__ b4,
    double* __restrict__ slots)
{
    __shared__ float hfs[100][64];
    __shared__ float cpm[4][64], cps[4][64], cdot[4][64], csby[4][64], cbym[4][64];
    __shared__ int   cidx[4][64], cbyidx[4][64];
    const int tid = threadIdx.x;
    const int lane = tid & 63;
    const int p = tid >> 6;
    const int b = blockIdx.x * 64 + lane;

    float h[HH];
    #pragma unroll
    for (int j = 0; j < HH; ++j) {
        const double s1 = slots[10 * 64 + j];
        const double s2 = slots[10 * 64 + HH + j];
        const double mu = s1 * (1.0 / 32768.0);
        const double var = s2 * (1.0 / 32768.0) - mu * mu;
        const float muf = (float)mu;
        const float rsig = 1.0f / sqrtf((float)var);
        const float hv = hs_buf[(j << 15) + b];
        h[j] = fmaxf(fmaf(g[j] * rsig, hv - muf, bb[j]), 0.f);
    }

    #pragma unroll
    for (int k = 0; k < 25; ++k) {
        const int f = p * 25 + k;
        float a = b3[f];
        #pragma unroll
        for (int i = 0; i < HH; ++i) a = fmaf(h[i], w3[i * 100 + f], a);
        hfs[f][lane] = fmaxf(a, 0.f);
    }
    __syncthreads();

    float lg[32];
    {
        const float* b4c = b4 + p * 32;
        #pragma unroll
        for (int u = 0; u < 32; ++u) lg[u] = b4c[u];
    }
    for (int k = 0; k < 100; ++k) {
        const float hv = hfs[k][lane];
        const float* wr = w4 + k * EE + p * 32;
        #pragma unroll
        for (int u = 0; u < 32; ++u) lg[u] = fmaf(hv, wr[u], lg[u]);
    }

    float pm = lg[0]; int pidx = 0;
    #pragma unroll
    for (int u = 1; u < 32; ++u) { if (lg[u] > pm) { pm = lg[u]; pidx = u; } }
    float ps = 0.f;
    #pragma unroll
    for (int u = 0; u < 32; ++u) ps += expf(lg[u] - pm);

    const float* byp = by + (size_t)b * EE + p * 32;
    float dotp = 0.f, sbyp = 0.f, bym = -3.402823e38f; int byi = 0;
    #pragma unroll
    for (int u4 = 0; u4 < 8; ++u4) {
        const float4 v = *(const float4*)(byp + u4 * 4);
        const int u = u4 * 4;
        if (v.x > bym) { bym = v.x; byi = u; }
        if (v.y > bym) { bym = v.y; byi = u + 1; }
        if (v.z > bym) { bym = v.z; byi = u + 2; }
        if (v.w > bym) { bym = v.w; byi = u + 3; }
        dotp = fmaf(v.x, lg[u], dotp);
        dotp = fmaf(v.y, lg[u + 1], dotp);
        dotp = fmaf(v.z, lg[u + 2], dotp);
        dotp = fmaf(v.w, lg[u + 3], dotp);
        sbyp += v.x + v.y + v.z + v.w;
    }

    cpm[p][lane] = pm;  cps[p][lane] = ps;  cdot[p][lane] = dotp;  csby[p][lane] = sbyp;
    cidx[p][lane] = p * 32 + pidx;
    cbym[p][lane] = bym; cbyidx[p][lane] = p * 32 + byi;
    __syncthreads();

    if (p == 0) {
        float gm = cpm[0][lane];
        #pragma unroll
        for (int q = 1; q < 4; ++q) gm = fmaxf(gm, cpm[q][lane]);
        float se = 0.f, dot = 0.f, sby = 0.f;
        #pragma unroll
        for (int q = 0; q < 4; ++q) {
            se  += cps[q][lane] * expf(cpm[q][lane] - gm);
            dot += cdot[q][lane];
            sby += csby[q][lane];
        }
        float cm = cpm[0][lane]; int am = cidx[0][lane];
        #pragma unroll
        for (int q = 1; q < 4; ++q) { if (cpm[q][lane] > cm) { cm = cpm[q][lane]; am = cidx[q][lane]; } }
        float bm = cbym[0][lane]; int byam = cbyidx[0][lane];
        #pragma unroll
        for (int q = 1; q < 4; ++q) { if (cbym[q][lane] > bm) { bm = cbym[q][lane]; byam = cbyidx[q][lane]; } }

        const float loss_i = -dot + (gm + logf(se)) * sby;
        const float acc_i = (am == byam) ? 1.f : 0.f;
        const float ls = waveRed(loss_i);
        const float as = waveRed(acc_i);
        if (lane == 0) {
            atomicAdd(&slots[704], (double)ls);
            atomicAdd(&slots[705], (double)as);
        }
    }
}

__global__ void finalize_kernel(const double* __restrict__ slots, float* __restrict__ out) {
    out[0] = (float)(slots[704] * (1.0 / 32768.0));
    out[1] = (float)(slots[705] * (1.0 / 32768.0));
}

extern "C" void kernel_launch(void* const* d_in, const int* in_sizes, int n_in,
                              void* d_out, int out_size, void* d_ws, size_t ws_size,
                              hipStream_t stream) {
    const float* bx = (const float*)d_in[0];
    const float* by = (const float*)d_in[1];
    const float* l  = (const float*)d_in[2];
    const float* e  = (const float*)d_in[3];
    const float* w1 = (const float*)d_in[4];
    const float* b1 = (const float*)d_in[5];
    const float* w2 = (const float*)d_in[6];
    const float* b2 = (const float*)d_in[7];
    const float* w3 = (const float*)d_in[8];
    const float* b3 = (const float*)d_in[9];
    const float* w4 = (const float*)d_in[10];
    const float* b4 = (const float*)d_in[11];
    const float* w  = (const float*)d_in[12];
    const float* c  = (const float*)d_in[13];
    const float* g  = (const float*)d_in[14];
    const float* bb = (const float*)d_in[15];

    double* slots = (double*)d_ws;
    float*  zcw   = (float*)((char*)d_ws + ZC_OFF);
    float*  hist  = (float*)((char*)d_ws + HIST_OFF);
    float*  hs    = (float*)((char*)d_ws + HS_OFF);
    unsigned int* W1A = (unsigned int*)((char*)d_ws + W1A_OFF);
    unsigned int* W2A = (unsigned int*)((char*)d_ws + W2A_OFF);
    unsigned int* CA  = (unsigned int*)((char*)d_ws + CA_OFF);
    float* b1f = (float*)((char*)d_ws + B1F_OFF);
    float* b2f = (float*)((char*)d_ws + B2F_OFF);
    float*  outp  = (float*)d_out;

    hipLaunchKernelGGL(setup_kernel, dim3(16), dim3(256), 0, stream,
                       w1, b1, w2, b2, c, W1A, W2A, CA, b1f, b2f, slots);
    hipLaunchKernelGGL(mlp_mfma, dim3(2816), dim3(256), 0, stream,
                       bx, W1A, W2A, CA, b1f, b2f, zcw);
#define LSTEP(T) hipLaunchKernelGGL((step_kernel<T>), dim3(256), dim3(256), 0, stream, \
                                    zcw, l, e, w, g, bb, hist, hs, slots)
    LSTEP(0); LSTEP(1); LSTEP(2); LSTEP(3); LSTEP(4); LSTEP(5);
    LSTEP(6); LSTEP(7); LSTEP(8); LSTEP(9); LSTEP(10);
#undef LSTEP
    hipLaunchKernelGGL(head_kernel, dim3(512), dim3(256), 0, stream,
                       hs, by, g, bb, w3, b3, w4, b4, slots);
    hipLaunchKernelGGL(finalize_kernel, dim3(1), dim3(1), 0, stream, slots, outp);
}

// Round 10
// 311.748 us; speedup vs baseline: 1.3894x; 1.3894x over previous
//
#include <hip/hip_runtime.h>
#include <hip/hip_bf16.h>

#define BATCH 32768
#define TT 11
#define EE 128
#define HH 20

typedef unsigned short ushort_t;
typedef __attribute__((ext_vector_type(8))) short short8;
typedef __attribute__((ext_vector_type(4))) float f32x4;

// ws layout (bytes):
//   [0 .. 8192)          : double slots[1024]
//   [8192 ..)            : float zc  [T][H][B]   (28835840)
//   [+..]                : float hist[T][H][B]   (28835840)
//   [+..]                : float hs  [H][B]      (2621440)
//   [+..]                : weight fragment region (2-split A-operands)
#define ZC_OFF   8192
#define HIST_OFF (8192 + 28835840)
#define HS_OFF   (8192 + 2*28835840)
#define W1A_OFF  (HS_OFF + 2621440)            // [4kt][4nt][2sp][64][4] u32 = 32768 B
#define W2A_OFF  (W1A_OFF + 32768)             // [2kt][7nt][2sp][64][4] u32 = 28672 B
#define CA_OFF   (W2A_OFF + 28672)             // [4kt][2nt][2sp][64][4] u32 = 16384 B
#define B1F_OFF  (CA_OFF + 16384)              // [4nt][64][4] f32 = 16384 B
#define B2F_OFF  (B1F_OFF + 16384)             // [7nt][64][4] f32 = 28672 B

__device__ __forceinline__ float waveRed(float v) {
    #pragma unroll
    for (int m = 32; m > 0; m >>= 1) v += __shfl_xor(v, m, 64);
    return v;
}

// 2-way bf16 split: v = h1 + h2 + O(2^-18 v)
__device__ __forceinline__ void split2(float v, ushort_t& a, ushort_t& b) {
    __hip_bfloat16 h1 = __float2bfloat16(v);
    float r1 = v - __bfloat162float(h1);     // exact (Sterbenz)
    __hip_bfloat16 h2 = __float2bfloat16(r1);
    a = *(ushort_t*)&h1; b = *(ushort_t*)&h2;
}

__device__ __forceinline__ f32x4 mfma16(short8 a, short8 b, f32x4 c) {
    return __builtin_amdgcn_mfma_f32_16x16x32_bf16(a, b, c, 0, 0, 0);
}

union FragU { uint4 v; unsigned int u[4]; short8 s; };

// ---------------- setup: pre-fragment weights (A-operand, 2 splits) + bias frags + zero slots ----------------
__global__ __launch_bounds__(256) void setup_kernel(
    const float* __restrict__ w1, const float* __restrict__ b1,
    const float* __restrict__ w2, const float* __restrict__ b2,
    const float* __restrict__ c,
    unsigned int* __restrict__ W1A, unsigned int* __restrict__ W2A, unsigned int* __restrict__ CA,
    float* __restrict__ b1f, float* __restrict__ b2f, double* __restrict__ slots)
{
    const int gid = blockIdx.x * 256 + threadIdx.x;
    const int nth = gridDim.x * 256;
    for (int i = gid; i < 1024; i += nth) slots[i] = 0.0;

    for (int i = gid; i < 4096; i += nth) {
        const int r = i & 3, lane = (i >> 2) & 63, nt = (i >> 8) & 3, kt = i >> 10;
        const int m = nt * 16 + (lane & 15);
        const int g = lane >> 4;
        int j0 = 2 * r, j1 = 2 * r + 1;
        int k0 = kt * 32 + ((j0 >= 4) ? 16 : 0) + 4 * g + (j0 & 3);
        int k1 = kt * 32 + ((j1 >= 4) ? 16 : 0) + 4 * g + (j1 & 3);
        float v0 = (m < 50) ? w1[k0 * 50 + m] : 0.f;
        float v1 = (m < 50) ? w1[k1 * 50 + m] : 0.f;
        ushort_t a0, a1, c0, c1;
        split2(v0, a0, a1); split2(v1, c0, c1);
        W1A[(((kt * 4 + nt) * 2 + 0) * 64 + lane) * 4 + r] = a0 | ((unsigned)c0 << 16);
        W1A[(((kt * 4 + nt) * 2 + 1) * 64 + lane) * 4 + r] = a1 | ((unsigned)c1 << 16);
    }
    for (int i = gid; i < 3584; i += nth) {
        const int r = i & 3, lane = (i >> 2) & 63, rest = i >> 8;
        const int nt = rest % 7, kt = rest / 7;
        const int m = nt * 16 + (lane & 15);
        const int g = lane >> 4;
        int j0 = 2 * r, j1 = 2 * r + 1;
        int k0 = kt * 32 + ((j0 >= 4) ? 16 : 0) + 4 * g + (j0 & 3);
        int k1 = kt * 32 + ((j1 >= 4) ? 16 : 0) + 4 * g + (j1 & 3);
        float v0 = (m < 100 && k0 < 50) ? w2[k0 * 100 + m] : 0.f;
        float v1 = (m < 100 && k1 < 50) ? w2[k1 * 100 + m] : 0.f;
        ushort_t a0, a1, c0, c1;
        split2(v0, a0, a1); split2(v1, c0, c1);
        W2A[(((kt * 7 + nt) * 2 + 0) * 64 + lane) * 4 + r] = a0 | ((unsigned)c0 << 16);
        W2A[(((kt * 7 + nt) * 2 + 1) * 64 + lane) * 4 + r] = a1 | ((unsigned)c1 << 16);
    }
    for (int i = gid; i < 2048; i += nth) {
        const int r = i & 3, lane = (i >> 2) & 63, rest = i >> 8;
        const int nt = rest & 1, kt = rest >> 1;
        const int m = nt * 16 + (lane & 15);
        const int g = lane >> 4;
        int j0 = 2 * r, j1 = 2 * r + 1;
        int k0 = kt * 32 + ((j0 >= 4) ? 16 : 0) + 4 * g + (j0 & 3);
        int k1 = kt * 32 + ((j1 >= 4) ? 16 : 0) + 4 * g + (j1 & 3);
        float v0 = (m < 20 && k0 < 100) ? c[k0 * 20 + m] : 0.f;
        float v1 = (m < 20 && k1 < 100) ? c[k1 * 20 + m] : 0.f;
        ushort_t a0, a1, c0, c1;
        split2(v0, a0, a1); split2(v1, c0, c1);
        CA[(((kt * 2 + nt) * 2 + 0) * 64 + lane) * 4 + r] = a0 | ((unsigned)c0 << 16);
        CA[(((kt * 2 + nt) * 2 + 1) * 64 + lane) * 4 + r] = a1 | ((unsigned)c1 << 16);
    }
    for (int i = gid; i < 1024; i += nth) {
        const int r = i & 3, lane = (i >> 2) & 63, nt = i >> 8;
        const int n = nt * 16 + 4 * (lane >> 4) + r;
        b1f[i] = (n < 50) ? b1[n] : 0.f;
    }
    for (int i = gid; i < 1792; i += nth) {
        const int r = i & 3, lane = (i >> 2) & 63, nt = i >> 8;
        const int n = nt * 16 + 4 * (lane >> 4) + r;
        b2f[i] = (n < 100) ? b2[n] : 0.f;
    }
}

// build B-frag pair (2 splits) from the two float4s of one kt chunk
__device__ __forceinline__ void buildB(const float4 lo, const float4 hi, FragU& B0, FragU& B1) {
    ushort_t a[8], b[8];
    split2(lo.x, a[0], b[0]); split2(lo.y, a[1], b[1]);
    split2(lo.z, a[2], b[2]); split2(lo.w, a[3], b[3]);
    split2(hi.x, a[4], b[4]); split2(hi.y, a[5], b[5]);
    split2(hi.z, a[6], b[6]); split2(hi.w, a[7], b[7]);
    #pragma unroll
    for (int r = 0; r < 4; ++r) {
        B0.u[r] = a[2 * r] | ((unsigned)a[2 * r + 1] << 16);
        B1.u[r] = b[2 * r] | ((unsigned)b[2 * r + 1] << 16);
    }
}

// bias+relu+split of one D quadrant into B-frag halves
__device__ __forceinline__ void actSplit(const f32x4 D, const float4 bv, int half, FragU* B) {
    #pragma unroll
    for (int rp = 0; rp < 2; ++rp) {
        float v0 = fmaxf(D[2 * rp]     + bv[2 * rp],     0.f);
        float v1 = fmaxf(D[2 * rp + 1] + bv[2 * rp + 1], 0.f);
        ushort_t s00, s01, s10, s11;
        split2(v0, s00, s01); split2(v1, s10, s11);
        B[0].u[half * 2 + rp] = s00 | ((unsigned)s10 << 16);
        B[1].u[half * 2 + rp] = s01 | ((unsigned)s11 << 16);
    }
}

// ---------------- MFMA input MLP v3 (R9, proven 117 us / absmax 0): reg-direct B, 2 m-tiles/wave ----------------
__global__ __launch_bounds__(256) void mlp_mfma(
    const float* __restrict__ bx,
    const unsigned int* __restrict__ W1A, const unsigned int* __restrict__ W2A,
    const unsigned int* __restrict__ CA,
    const float* __restrict__ b1f, const float* __restrict__ b2f,
    float* __restrict__ zc)
{
    const int tid = threadIdx.x;
    const int lane = tid & 63, wv = tid >> 6;
    const int R = (blockIdx.x * 4 + wv) * 32;     // 2816 blocks * 4 waves * 32 rows
    const int t = R >> 15;
    const int bbase = R & (BATCH - 1);
    const int srow = lane & 15, g = lane >> 4;

    const float* xp0 = bx + ((size_t)(bbase + srow) * TT + t) * EE;
    const float* xp1 = bx + ((size_t)(bbase + 16 + srow) * TT + t) * EE;

    float4 xl0[4], xh0[4], xl1[4], xh1[4];
    #pragma unroll
    for (int kt = 0; kt < 4; ++kt) {
        xl0[kt] = *(const float4*)(xp0 + kt * 32 + 4 * g);
        xh0[kt] = *(const float4*)(xp0 + kt * 32 + 16 + 4 * g);
        xl1[kt] = *(const float4*)(xp1 + kt * 32 + 4 * g);
        xh1[kt] = *(const float4*)(xp1 + kt * 32 + 16 + 4 * g);
    }

    const uint4* W1A4 = (const uint4*)W1A;
    const uint4* W2A4 = (const uint4*)W2A;
    const uint4* CA4  = (const uint4*)CA;
    const float4* b1f4 = (const float4*)b1f;
    const float4* b2f4 = (const float4*)b2f;

    f32x4 D1a[4], D1b[4];
    #pragma unroll
    for (int nt = 0; nt < 4; ++nt) { D1a[nt] = (f32x4){0,0,0,0}; D1b[nt] = (f32x4){0,0,0,0}; }
    #pragma unroll
    for (int kt = 0; kt < 4; ++kt) {
        FragU Ba[2], Bb[2];
        buildB(xl0[kt], xh0[kt], Ba[0], Ba[1]);
        buildB(xl1[kt], xh1[kt], Bb[0], Bb[1]);
        #pragma unroll
        for (int nt = 0; nt < 4; ++nt) {
            FragU A0, A1;
            A0.v = W1A4[((kt * 4 + nt) * 2 + 0) * 64 + lane];
            A1.v = W1A4[((kt * 4 + nt) * 2 + 1) * 64 + lane];
            D1a[nt] = mfma16(A1.s, Ba[0].s, D1a[nt]);
            D1a[nt] = mfma16(A0.s, Ba[1].s, D1a[nt]);
            D1a[nt] = mfma16(A0.s, Ba[0].s, D1a[nt]);
            D1b[nt] = mfma16(A1.s, Bb[0].s, D1b[nt]);
            D1b[nt] = mfma16(A0.s, Bb[1].s, D1b[nt]);
            D1b[nt] = mfma16(A0.s, Bb[0].s, D1b[nt]);
        }
    }

    f32x4 D2a[7], D2b[7];
    #pragma unroll
    for (int nt = 0; nt < 7; ++nt) { D2a[nt] = (f32x4){0,0,0,0}; D2b[nt] = (f32x4){0,0,0,0}; }
    #pragma unroll
    for (int kt2 = 0; kt2 < 2; ++kt2) {
        FragU Ba[2], Bb[2];
        #pragma unroll
        for (int half = 0; half < 2; ++half) {
            const int nt = 2 * kt2 + half;
            const float4 bv = b1f4[nt * 64 + lane];
            actSplit(D1a[nt], bv, half, Ba);
            actSplit(D1b[nt], bv, half, Bb);
        }
        #pragma unroll
        for (int nt2 = 0; nt2 < 7; ++nt2) {
            FragU A0, A1;
            A0.v = W2A4[((kt2 * 7 + nt2) * 2 + 0) * 64 + lane];
            A1.v = W2A4[((kt2 * 7 + nt2) * 2 + 1) * 64 + lane];
            D2a[nt2] = mfma16(A1.s, Ba[0].s, D2a[nt2]);
            D2a[nt2] = mfma16(A0.s, Ba[1].s, D2a[nt2]);
            D2a[nt2] = mfma16(A0.s, Ba[0].s, D2a[nt2]);
            D2b[nt2] = mfma16(A1.s, Bb[0].s, D2b[nt2]);
            D2b[nt2] = mfma16(A0.s, Bb[1].s, D2b[nt2]);
            D2b[nt2] = mfma16(A0.s, Bb[0].s, D2b[nt2]);
        }
    }

    f32x4 D3a[2], D3b[2];
    D3a[0] = (f32x4){0,0,0,0}; D3a[1] = (f32x4){0,0,0,0};
    D3b[0] = (f32x4){0,0,0,0}; D3b[1] = (f32x4){0,0,0,0};
    #pragma unroll
    for (int kt3 = 0; kt3 < 4; ++kt3) {
        FragU Ba[2], Bb[2];
        #pragma unroll
        for (int half = 0; half < 2; ++half) {
            const int nt = 2 * kt3 + half;
            if (nt < 7) {
                const float4 bv = b2f4[nt * 64 + lane];
                actSplit(D2a[nt], bv, half, Ba);
                actSplit(D2b[nt], bv, half, Bb);
            } else {
                Ba[0].u[2] = Ba[0].u[3] = 0u; Ba[1].u[2] = Ba[1].u[3] = 0u;
                Bb[0].u[2] = Bb[0].u[3] = 0u; Bb[1].u[2] = Bb[1].u[3] = 0u;
            }
        }
        #pragma unroll
        for (int nt3 = 0; nt3 < 2; ++nt3) {
            FragU A0, A1;
            A0.v = CA4[((kt3 * 2 + nt3) * 2 + 0) * 64 + lane];
            A1.v = CA4[((kt3 * 2 + nt3) * 2 + 1) * 64 + lane];
            D3a[nt3] = mfma16(A1.s, Ba[0].s, D3a[nt3]);
            D3a[nt3] = mfma16(A0.s, Ba[1].s, D3a[nt3]);
            D3a[nt3] = mfma16(A0.s, Ba[0].s, D3a[nt3]);
            D3b[nt3] = mfma16(A1.s, Bb[0].s, D3b[nt3]);
            D3b[nt3] = mfma16(A0.s, Bb[1].s, D3b[nt3]);
            D3b[nt3] = mfma16(A0.s, Bb[0].s, D3b[nt3]);
        }
    }

    const int bcol0 = bbase + srow, bcol1 = bbase + 16 + srow;
    #pragma unroll
    for (int r = 0; r < 4; ++r) {
        const int h = 4 * g + r;
        zc[((size_t)(t * HH + h) << 15) + bcol0] = D3a[0][r];
        zc[((size_t)(t * HH + h) << 15) + bcol1] = D3b[0][r];
    }
    if (g == 0) {
        #pragma unroll
        for (int r = 0; r < 4; ++r) {
            zc[((size_t)(t * HH + 16 + r) << 15) + bcol0] = D3a[1][r];
            zc[((size_t)(t * HH + 16 + r) << 15) + bcol1] = D3b[1][r];
        }
    }
}

// ---------------- Kernel B (x11): R6 proven structure + depth-2 pipelined s-loop ----------------
__global__ __launch_bounds__(256) void step_kernel(
    const float* __restrict__ zc, const float* __restrict__ lp, const float* __restrict__ ep,
    const float* __restrict__ w, const float* __restrict__ g, const float* __restrict__ bb,
    float* __restrict__ hist, float* __restrict__ hs_buf, double* __restrict__ slots, int t)
{
    __shared__ float red[4][40];
    const int tid = threadIdx.x;
    const int p = tid & 1;
    const int sb = tid >> 1;
    const int b = blockIdx.x * 128 + sb;
    const int lane = tid & 63, wv = tid >> 6;
    const int jb = 10 * p;
    const float l0 = lp[0], e0 = ep[0];

    float h[10];
    if (t == 0) {
        #pragma unroll
        for (int jj = 0; jj < 10; ++jj) h[jj] = 0.f;
    } else {
        #pragma unroll
        for (int jj = 0; jj < 10; ++jj) {
            const int j = jb + jj;
            const double s1 = slots[(t - 1) * 64 + j];
            const double s2 = slots[(t - 1) * 64 + HH + j];
            const double mu = s1 * (1.0 / 32768.0);
            const double var = s2 * (1.0 / 32768.0) - mu * mu;
            const float muf = (float)mu;
            const float rsig = 1.0f / sqrtf((float)var);
            const float hv = hs_buf[(j << 15) + b];
            h[jj] = fmaxf(fmaf(g[j] * rsig, hv - muf, bb[j]), 0.f);
        }
    }

    float zct[10];
    #pragma unroll
    for (int jj = 0; jj < 10; ++jj) zct[jj] = zc[((t * HH + jb + jj) << 15) + b];

    float hn[10];
    {
        float po[20];
        #pragma unroll
        for (int j = 0; j < 20; ++j) {
            float a = 0.f;
            #pragma unroll
            for (int ii = 0; ii < 10; ++ii) a = fmaf(h[ii], w[(jb + ii) * HH + j], a);
            po[j] = a;
        }
        #pragma unroll
        for (int jj = 0; jj < 10; ++jj) {
            const float mine = p ? po[10 + jj] : po[jj];
            const float send = p ? po[jj] : po[10 + jj];
            const float recv = __shfl_xor(send, 1, 64);
            hn[jj] = fmaxf(mine + recv + zct[jj], 0.f);
        }
    }
    #pragma unroll
    for (int jj = 0; jj < 10; ++jj) hist[((t * HH + jb + jj) << 15) + b] = hn[jj];

    // pv = e * sum_{s<=t} l^(t-s) (hn . hn_s) hn_s
    float pv[10];
    {
        float dp = 0.f;
        #pragma unroll
        for (int jj = 0; jj < 10; ++jj) dp = fmaf(hn[jj], hn[jj], dp);
        const float d = dp + __shfl_xor(dp, 1, 64);
        const float cd = e0 * d;
        #pragma unroll
        for (int jj = 0; jj < 10; ++jj) pv[jj] = cd * hn[jj];
    }
    if (t > 0) {
        float coef = e0 * l0;
        float tvc[10];
        #pragma unroll
        for (int jj = 0; jj < 10; ++jj)
            tvc[jj] = hist[(((t - 1) * HH + jb + jj) << 15) + b];
        #pragma unroll 1
        for (int s = t - 1; s >= 0; --s) {
            float tvn[10];                     // next iteration's history, issued before the dot
            if (s > 0) {
                #pragma unroll
                for (int jj = 0; jj < 10; ++jj)
                    tvn[jj] = hist[(((s - 1) * HH + jb + jj) << 15) + b];
            }
            float dp = 0.f;
            #pragma unroll
            for (int jj = 0; jj < 10; ++jj) dp = fmaf(hn[jj], tvc[jj], dp);
            const float d = dp + __shfl_xor(dp, 1, 64);
            const float cd = coef * d;
            #pragma unroll
            for (int jj = 0; jj < 10; ++jj) pv[jj] = fmaf(cd, tvc[jj], pv[jj]);
            coef *= l0;
            if (s > 0) {
                #pragma unroll
                for (int jj = 0; jj < 10; ++jj) tvc[jj] = tvn[jj];
            }
        }
    }

    float hs[10];
    {
        float po[20];
        #pragma unroll
        for (int j = 0; j < 20; ++j) {
            float a = 0.f;
            #pragma unroll
            for (int ii = 0; ii < 10; ++ii) a = fmaf(hn[ii], w[(jb + ii) * HH + j], a);
            po[j] = a;
        }
        #pragma unroll
        for (int jj = 0; jj < 10; ++jj) {
            const float mine = p ? po[10 + jj] : po[jj];
            const float send = p ? po[jj] : po[10 + jj];
            const float recv = __shfl_xor(send, 1, 64);
            hs[jj] = mine + recv + zct[jj] + pv[jj];
            hs_buf[((jb + jj) << 15) + b] = hs[jj];
        }
    }

    float sm[10], sq[10];
    #pragma unroll
    for (int jj = 0; jj < 10; ++jj) { sm[jj] = hs[jj]; sq[jj] = hs[jj] * hs[jj]; }
    #pragma unroll
    for (int m = 2; m <= 32; m <<= 1) {
        #pragma unroll
        for (int jj = 0; jj < 10; ++jj) {
            sm[jj] += __shfl_xor(sm[jj], m, 64);
            sq[jj] += __shfl_xor(sq[jj], m, 64);
        }
    }
    if (lane < 2) {
        #pragma unroll
        for (int jj = 0; jj < 10; ++jj) {
            red[wv][jb + jj] = sm[jj];
            red[wv][20 + jb + jj] = sq[jj];
        }
    }
    __syncthreads();
    if (tid < 40) {
        atomicAdd(&slots[t * 64 + tid],
                  (double)(red[0][tid] + red[1][tid] + red[2][tid] + red[3][tid]));
    }
}

// ---------------- head: 4 waves co-operate on 64 samples (proven) ----------------
__global__ __launch_bounds__(256, 2) void head_kernel(
    const float* __restrict__ hs_buf, const float* __restrict__ by,
    const float* __restrict__ g, const float* __restrict__ bb,
    const float* __restrict__ w3, const float* __restrict__ b3,
    const float* __restrict__ w4, const float* __restrict__ b4,
    double* __restrict__ slots)
{
    __shared__ float hfs[100][64];
    __shared__ float cpm[4][64], cps[4][64], cdot[4][64], csby[4][64], cbym[4][64];
    __shared__ int   cidx[4][64], cbyidx[4][64];
    const int tid = threadIdx.x;
    const int lane = tid & 63;
    const int p = tid >> 6;
    const int b = blockIdx.x * 64 + lane;

    float h[HH];
    #pragma unroll
    for (int j = 0; j < HH; ++j) {
        const double s1 = slots[10 * 64 + j];
        const double s2 = slots[10 * 64 + HH + j];
        const double mu = s1 * (1.0 / 32768.0);
        const double var = s2 * (1.0 / 32768.0) - mu * mu;
        const float muf = (float)mu;
        const float rsig = 1.0f / sqrtf((float)var);
        const float hv = hs_buf[(j << 15) + b];
        h[j] = fmaxf(fmaf(g[j] * rsig, hv - muf, bb[j]), 0.f);
    }

    #pragma unroll
    for (int k = 0; k < 25; ++k) {
        const int f = p * 25 + k;
        float a = b3[f];
        #pragma unroll
        for (int i = 0; i < HH; ++i) a = fmaf(h[i], w3[i * 100 + f], a);
        hfs[f][lane] = fmaxf(a, 0.f);
    }
    __syncthreads();

    float lg[32];
    {
        const float* b4c = b4 + p * 32;
        #pragma unroll
        for (int u = 0; u < 32; ++u) lg[u] = b4c[u];
    }
    for (int k = 0; k < 100; ++k) {
        const float hv = hfs[k][lane];
        const float* wr = w4 + k * EE + p * 32;
        #pragma unroll
        for (int u = 0; u < 32; ++u) lg[u] = fmaf(hv, wr[u], lg[u]);
    }

    float pm = lg[0]; int pidx = 0;
    #pragma unroll
    for (int u = 1; u < 32; ++u) { if (lg[u] > pm) { pm = lg[u]; pidx = u; } }
    float ps = 0.f;
    #pragma unroll
    for (int u = 0; u < 32; ++u) ps += expf(lg[u] - pm);

    const float* byp = by + (size_t)b * EE + p * 32;
    float dotp = 0.f, sbyp = 0.f, bym = -3.402823e38f; int byi = 0;
    #pragma unroll
    for (int u4 = 0; u4 < 8; ++u4) {
        const float4 v = *(const float4*)(byp + u4 * 4);
        const int u = u4 * 4;
        if (v.x > bym) { bym = v.x; byi = u; }
        if (v.y > bym) { bym = v.y; byi = u + 1; }
        if (v.z > bym) { bym = v.z; byi = u + 2; }
        if (v.w > bym) { bym = v.w; byi = u + 3; }
        dotp = fmaf(v.x, lg[u], dotp);
        dotp = fmaf(v.y, lg[u + 1], dotp);
        dotp = fmaf(v.z, lg[u + 2], dotp);
        dotp = fmaf(v.w, lg[u + 3], dotp);
        sbyp += v.x + v.y + v.z + v.w;
    }

    cpm[p][lane] = pm;  cps[p][lane] = ps;  cdot[p][lane] = dotp;  csby[p][lane] = sbyp;
    cidx[p][lane] = p * 32 + pidx;
    cbym[p][lane] = bym; cbyidx[p][lane] = p * 32 + byi;
    __syncthreads();

    if (p == 0) {
        float gm = cpm[0][lane];
        #pragma unroll
        for (int q = 1; q < 4; ++q) gm = fmaxf(gm, cpm[q][lane]);
        float se = 0.f, dot = 0.f, sby = 0.f;
        #pragma unroll
        for (int q = 0; q < 4; ++q) {
            se  += cps[q][lane] * expf(cpm[q][lane] - gm);
            dot += cdot[q][lane];
            sby += csby[q][lane];
        }
        float cm = cpm[0][lane]; int am = cidx[0][lane];
        #pragma unroll
        for (int q = 1; q < 4; ++q) { if (cpm[q][lane] > cm) { cm = cpm[q][lane]; am = cidx[q][lane]; } }
        float bm = cbym[0][lane]; int byam = cbyidx[0][lane];
        #pragma unroll
        for (int q = 1; q < 4; ++q) { if (cbym[q][lane] > bm) { bm = cbym[q][lane]; byam = cbyidx[q][lane]; } }

        const float loss_i = -dot + (gm + logf(se)) * sby;
        const float acc_i = (am == byam) ? 1.f : 0.f;
        const float ls = waveRed(loss_i);
        const float as = waveRed(acc_i);
        if (lane == 0) {
            atomicAdd(&slots[704], (double)ls);
            atomicAdd(&slots[705], (double)as);
        }
    }
}

__global__ void finalize_kernel(const double* __restrict__ slots, float* __restrict__ out) {
    out[0] = (float)(slots[704] * (1.0 / 32768.0));
    out[1] = (float)(slots[705] * (1.0 / 32768.0));
}

extern "C" void kernel_launch(void* const* d_in, const int* in_sizes, int n_in,
                              void* d_out, int out_size, void* d_ws, size_t ws_size,
                              hipStream_t stream) {
    const float* bx = (const float*)d_in[0];
    const float* by = (const float*)d_in[1];
    const float* l  = (const float*)d_in[2];
    const float* e  = (const float*)d_in[3];
    const float* w1 = (const float*)d_in[4];
    const float* b1 = (const float*)d_in[5];
    const float* w2 = (const float*)d_in[6];
    const float* b2 = (const float*)d_in[7];
    const float* w3 = (const float*)d_in[8];
    const float* b3 = (const float*)d_in[9];
    const float* w4 = (const float*)d_in[10];
    const float* b4 = (const float*)d_in[11];
    const float* w  = (const float*)d_in[12];
    const float* c  = (const float*)d_in[13];
    const float* g  = (const float*)d_in[14];
    const float* bb = (const float*)d_in[15];

    double* slots = (double*)d_ws;
    float*  zcw   = (float*)((char*)d_ws + ZC_OFF);
    float*  hist  = (float*)((char*)d_ws + HIST_OFF);
    float*  hs    = (float*)((char*)d_ws + HS_OFF);
    unsigned int* W1A = (unsigned int*)((char*)d_ws + W1A_OFF);
    unsigned int* W2A = (unsigned int*)((char*)d_ws + W2A_OFF);
    unsigned int* CA  = (unsigned int*)((char*)d_ws + CA_OFF);
    float* b1f = (float*)((char*)d_ws + B1F_OFF);
    float* b2f = (float*)((char*)d_ws + B2F_OFF);
    float*  outp  = (float*)d_out;

    hipLaunchKernelGGL(setup_kernel, dim3(16), dim3(256), 0, stream,
                       w1, b1, w2, b2, c, W1A, W2A, CA, b1f, b2f, slots);
    hipLaunchKernelGGL(mlp_mfma, dim3(2816), dim3(256), 0, stream,
                       bx, W1A, W2A, CA, b1f, b2f, zcw);
    for (int t = 0; t < TT; ++t) {
        hipLaunchKernelGGL(step_kernel, dim3(256), dim3(256), 0, stream,
                           zcw, l, e, w, g, bb, hist, hs, slots, t);
    }
    hipLaunchKernelGGL(head_kernel, dim3(512), dim3(256), 0, stream,
                       hs, by, g, bb, w3, b3, w4, b4, slots);
    hipLaunchKernelGGL(finalize_kernel, dim3(1), dim3(1), 0, stream, slots, outp);
}